// Round 6
// baseline (121.897 us; speedup 1.0000x reference)
//
#include <hip/hip_runtime.h>

// SparseDopplerAttention on gfx950 — R8b (resubmit of R8; round 5 failed with a
// container-level infra error, no compile/test/profile output; source audited:
// no divergent barriers, all LDS/workspace accesses in-bounds, launch pattern
// identical to the R6/R7 rounds that passed).
//
// R8: key-split for 2-blocks/CU occupancy.
// Identity (R3): out[q] = (sum_k P[q,k]*vsum[k]) / (sum_k P[q,k]),
//   vsum[k] = x[k] . colsum(Wv) + sum(bv)  (fp32) — V GEMM / PV GEMM eliminated.
// R7 post-mortem: 51 -> ~31 us via LDS-staged weights; remaining limit is grid
// shape: grid 256 == CU count -> 1 block/CU (4 waves/SIMD) forever. R8 splits
// each range into TWO KEY-HALF blocks (grid 512):
//   - K GEMM halves per block (built by the 8 waves whose own query rows
//     coincide with the key half -> zero extra x loads, no R4-style dup)
//   - Q GEMM per wave for its own 32 queries (duplicated 2x, ~1.5 us chip)
//   - Phase B: 512q x 256k per block -> partial {osum,lsum} to workspace,
//     tiny combine kernel divides. Total LDS traffic unchanged.
//   - LDS 59.4 KB/block -> 2 blocks/CU = 32 waves/CU (8/SIMD) hides the
//     ds_read->MFMA->exp chains and barrier drains that dominate at 16 waves.
// Q-transpose scratch: per-wave 2 KB region inside Kb, freed by a barrier
// before builders overwrite Kb with K. Fallback: proven R7 mono-kernel.

#define SCALE 0.18033688011112042f   // log2(e)/8

typedef __bf16 bf16;
typedef bf16 v4bf __attribute__((ext_vector_type(4)));
typedef bf16 v8bf __attribute__((ext_vector_type(8)));
typedef float v4f __attribute__((ext_vector_type(4)));

__device__ __forceinline__ v8bf pk8(float4 a, float4 b) {
    v8bf r;
    r[0] = (bf16)a.x; r[1] = (bf16)a.y; r[2] = (bf16)a.z; r[3] = (bf16)a.w;
    r[4] = (bf16)b.x; r[5] = (bf16)b.y; r[6] = (bf16)b.z; r[7] = (bf16)b.w;
    return r;
}
__device__ __forceinline__ float d4(float4 a, v4f w) {
    return a.x * w[0] + a.y * w[1] + a.z * w[2] + a.w * w[3];
}

// ---------------- main kernel: block = (range, key-half), grid 512 ----------------
__global__ __launch_bounds__(1024, 8)
void sda_split(const float* __restrict__ power,
               const int*   __restrict__ ele_i,
               const int*   __restrict__ azi_i,
               const float* __restrict__ ele_t,
               const float* __restrict__ azi_t,
               const float* __restrict__ Wq, const float* __restrict__ bq,
               const float* __restrict__ Wk, const float* __restrict__ bk,
               const float* __restrict__ Wv, const float* __restrict__ bv,
               float2* __restrict__ part)   // [q][khalf] = {osum, lsum}
{
    extern __shared__ char smem[];
    char*  Kb   = smem;                    // 32 KB: 256 key rows x 128 B (early: Q scratch, wave*2048)
    float* vsum = (float*)(smem + 32768);  // 256 f32 (local key idx)
    float* wvs  = (float*)(smem + 33792);  // 96 col-sums of Wv + [96]=sum(bv)
    bf16*  WqL  = (bf16*)(smem + 34304);   // 12 KB bf16 [64][96]
    bf16*  WkL  = (bf16*)(smem + 46592);   // 12 KB
    float* bqL  = (float*)(smem + 58880);  // 64 f32
    float* bkL  = (float*)(smem + 59136);  // 64 f32  -> total 59392 B

    const int tid  = threadIdx.x;
    const int wave = tid >> 6;
    const int lane = tid & 63;
    const int l15  = lane & 15;
    const int quad = lane >> 4;

    // XCD-pair swizzle: bid = 8c+x -> lj = 64x+c; pair (lj, lj^1) shares an XCD,
    // so a range's two key-half blocks share its power rows + Q work in one L2.
    const int bid   = blockIdx.x;
    const int lj    = ((bid & 7) << 6) | (bid >> 3);
    const int range = lj >> 1;
    const int khalf = lj & 1;
    const int is_b  = (wave >> 3) == khalf;   // builder waves: query rows == key rows
    const int wb    = wave & 7;

    // ---- stage weights (bf16), biases, Wv col-sums ----
#pragma unroll
    for (int i = 0; i < 6; i++) {
        int idx = tid + i * 1024;            // 6144 each
        WqL[idx] = (bf16)Wq[idx];
        WkL[idx] = (bf16)Wk[idx];
    }
    if (tid < 64) { bqL[tid] = bq[tid]; bkL[tid] = bk[tid]; }
    if (tid < 96) {
        float s = 0.f;
#pragma unroll 16
        for (int r = 0; r < 64; r++) s += Wv[r * 96 + tid];
        wvs[tid] = s;
    } else if (tid == 96) {
        float s = 0.f;
#pragma unroll
        for (int d = 0; d < 64; d++) s += bv[d];
        wvs[96] = s;
    }
    __syncthreads();

    // ---- x fragments for own 32 query rows (+ vsum for builders) ----
    v8bf xa[2][3];
#pragma unroll
    for (int mt = 0; mt < 2; mt++) {
        int row = range * 512 + wave * 32 + mt * 16 + l15;
        const float* pr = power + (size_t)row * 64;
        float4 a0 = *(const float4*)(pr + quad * 8);
        float4 a1 = *(const float4*)(pr + quad * 8 + 4);
        xa[mt][0] = pk8(a0, a1);
        float4 a2 = *(const float4*)(pr + 32 + quad * 8);
        float4 a3 = *(const float4*)(pr + 32 + quad * 8 + 4);
        xa[mt][1] = pk8(a2, a3);
        int ie = ele_i[row];
        int ia = azi_i[row];
        const float* tb = (quad < 2) ? (ele_t + ie * 16 + quad * 8)
                                     : (azi_t + ia * 16 + (quad - 2) * 8);
        float4 a4 = *(const float4*)tb;
        float4 a5 = *(const float4*)(tb + 4);
        xa[mt][2] = pk8(a4, a5);
        if (is_b) {   // wave-uniform branch; builders' key rows == these rows
            float d = d4(a0, *(const v4f*)(wvs + quad * 8))
                    + d4(a1, *(const v4f*)(wvs + quad * 8 + 4))
                    + d4(a2, *(const v4f*)(wvs + 32 + quad * 8))
                    + d4(a3, *(const v4f*)(wvs + 32 + quad * 8 + 4))
                    + d4(a4, *(const v4f*)(wvs + 64 + quad * 8))
                    + d4(a5, *(const v4f*)(wvs + 64 + quad * 8 + 4));
            d += __shfl_xor(d, 16);
            d += __shfl_xor(d, 32);
            if (quad == 0) vsum[wb * 32 + mt * 16 + l15] = d + wvs[96];
        }
    }

    // ---- Q^T = Wq @ x^T per ntr, 16-row scratch at Kb + wave*2048 ----
    char* Sw = Kb + wave * 2048;
    v8bf qf[2][2];
#pragma unroll
    for (int ntr = 0; ntr < 2; ntr++) {
#pragma unroll 1
        for (int mtd = 0; mtd < 4; mtd++) {
            const bf16* wrow = WqL + (mtd * 16 + l15) * 96;
            v8bf wq3[3];
#pragma unroll
            for (int kt = 0; kt < 3; kt++)
                wq3[kt] = *(const v8bf*)(wrow + kt * 32 + quad * 8);
            float4 bq4 = *(const float4*)(bqL + mtd * 16 + quad * 4);
            v4f acc = {0.f, 0.f, 0.f, 0.f};
#pragma unroll
            for (int kt = 0; kt < 3; kt++)
                acc = __builtin_amdgcn_mfma_f32_16x16x32_bf16(wq3[kt], xa[ntr][kt], acc, 0, 0, 0);
            v4bf o;
            o[0] = (bf16)((acc[0] + bq4.x) * SCALE);
            o[1] = (bf16)((acc[1] + bq4.y) * SCALE);
            o[2] = (bf16)((acc[2] + bq4.z) * SCALE);
            o[3] = (bf16)((acc[3] + bq4.w) * SCALE);
            *(v4bf*)(Sw + l15 * 128 +
                     ((((mtd * 2 + (quad >> 1)) ^ (l15 & 7)) << 4) | ((quad & 1) << 3))) = o;
        }
        // same-wave DS ops are in-order: read this ntr's fragments back
#pragma unroll
        for (int kt = 0; kt < 2; kt++)
            qf[ntr][kt] = *(const v8bf*)(Sw + l15 * 128 + (((kt * 4 + quad) ^ (l15 & 7)) << 4));
    }
    __syncthreads();   // all Q-scratch reads done before K overwrites Kb

    // ---- builders: K^T = Wk @ x^T into Kb (256 rows, swizzled) ----
    if (is_b) {
#pragma unroll 1
        for (int mtd = 0; mtd < 4; mtd++) {
            const bf16* wrow = WkL + (mtd * 16 + l15) * 96;
            v8bf wk3[3];
#pragma unroll
            for (int kt = 0; kt < 3; kt++)
                wk3[kt] = *(const v8bf*)(wrow + kt * 32 + quad * 8);
            float4 bk4 = *(const float4*)(bkL + mtd * 16 + quad * 4);
#pragma unroll
            for (int ntr = 0; ntr < 2; ntr++) {
                v4f acc = {0.f, 0.f, 0.f, 0.f};
#pragma unroll
                for (int kt = 0; kt < 3; kt++)
                    acc = __builtin_amdgcn_mfma_f32_16x16x32_bf16(wk3[kt], xa[ntr][kt], acc, 0, 0, 0);
                int keyb = wb * 32 + ntr * 16 + l15;
                v4bf o;
                o[0] = (bf16)(acc[0] + bk4.x);
                o[1] = (bf16)(acc[1] + bk4.y);
                o[2] = (bf16)(acc[2] + bk4.z);
                o[3] = (bf16)(acc[3] + bk4.w);
                *(v4bf*)(Kb + keyb * 128 +
                         ((((mtd * 2 + (quad >> 1)) ^ (keyb & 7)) << 4) | ((quad & 1) << 3))) = o;
            }
        }
    }
    __syncthreads();

    // ---- Phase B: S^T = K @ Q^T over 256 local keys, exp2, vsum-weighted sums ----
    float osum[2] = {0.f, 0.f};
    float lsum[2] = {0.f, 0.f};
#pragma unroll 2
    for (int t = 0; t < 8; t++) {
        v8bf kf[2][2];
#pragma unroll
        for (int mtk = 0; mtk < 2; mtk++)
#pragma unroll
            for (int kt = 0; kt < 2; kt++) {
                int key = t * 32 + mtk * 16 + l15;
                kf[mtk][kt] = *(const v8bf*)(Kb + key * 128 + (((kt * 4 + quad) ^ (key & 7)) << 4));
            }
        v4f vs[2];
#pragma unroll
        for (int mtk = 0; mtk < 2; mtk++)
            vs[mtk] = *(const v4f*)(vsum + t * 32 + mtk * 16 + quad * 4);
#pragma unroll
        for (int mtk = 0; mtk < 2; mtk++) {
#pragma unroll
            for (int nt = 0; nt < 2; nt++) {
                v4f acc = {0.f, 0.f, 0.f, 0.f};
                acc = __builtin_amdgcn_mfma_f32_16x16x32_bf16(kf[mtk][0], qf[nt][0], acc, 0, 0, 0);
                acc = __builtin_amdgcn_mfma_f32_16x16x32_bf16(kf[mtk][1], qf[nt][1], acc, 0, 0, 0);
                float p0 = __builtin_amdgcn_exp2f(acc[0]);
                float p1 = __builtin_amdgcn_exp2f(acc[1]);
                float p2 = __builtin_amdgcn_exp2f(acc[2]);
                float p3 = __builtin_amdgcn_exp2f(acc[3]);
                lsum[nt] += (p0 + p1) + (p2 + p3);
                osum[nt] += ((p0 * vs[mtk][0] + p1 * vs[mtk][1]) +
                             (p2 * vs[mtk][2] + p3 * vs[mtk][3]));
            }
        }
    }

    // ---- epilogue: quad-reduce, write partial {osum, lsum} ----
#pragma unroll
    for (int nt = 0; nt < 2; nt++) {
        float lv = lsum[nt];
        lv += __shfl_xor(lv, 16);
        lv += __shfl_xor(lv, 32);
        float ov = osum[nt];
        ov += __shfl_xor(ov, 16);
        ov += __shfl_xor(ov, 32);
        if (quad == 0) {
            int q = range * 512 + wave * 32 + nt * 16 + l15;
            float2 p; p.x = ov; p.y = lv;
            part[q * 2 + khalf] = p;
        }
    }
}

// ---------------- combine: out[q] = (o0+o1)/(l0+l1) ----------------
__global__ __launch_bounds__(1024, 8)
void sda_combine(const float4* __restrict__ part, float* __restrict__ out)
{
    int q = blockIdx.x * 1024 + threadIdx.x;
    float4 v = part[q];
    out[q] = (v.x + v.z) / (v.y + v.w);
}

// ---------------- fallback: proven R7 mono-kernel ----------------
__global__ __launch_bounds__(1024, 4)
void sda_mono(const float* __restrict__ power,
              const int*   __restrict__ ele_i,
              const int*   __restrict__ azi_i,
              const float* __restrict__ ele_t,
              const float* __restrict__ azi_t,
              const float* __restrict__ Wq, const float* __restrict__ bq,
              const float* __restrict__ Wk, const float* __restrict__ bk,
              const float* __restrict__ Wv, const float* __restrict__ bv,
              float* __restrict__ out)
{
    extern __shared__ char smem[];
    char*  Kb   = smem;
    float* vsum = (float*)(smem + 65536);
    float* wvs  = (float*)(smem + 67584);
    bf16*  WqL  = (bf16*)(smem + 68096);
    bf16*  WkL  = (bf16*)(smem + 80384);
    float* bqL  = (float*)(smem + 92672);
    float* bkL  = (float*)(smem + 92928);

    const int tid  = threadIdx.x;
    const int wave = tid >> 6;
    const int lane = tid & 63;
    const int l15  = lane & 15;
    const int quad = lane >> 4;
    const int rowbase = blockIdx.x * 512 + wave * 32;

#pragma unroll
    for (int i = 0; i < 6; i++) {
        int idx = tid + i * 1024;
        WqL[idx] = (bf16)Wq[idx];
        WkL[idx] = (bf16)Wk[idx];
    }
    if (tid < 64) { bqL[tid] = bq[tid]; bkL[tid] = bk[tid]; }
    if (tid < 96) {
        float s = 0.f;
#pragma unroll 16
        for (int r = 0; r < 64; r++) s += Wv[r * 96 + tid];
        wvs[tid] = s;
    } else if (tid == 96) {
        float s = 0.f;
#pragma unroll
        for (int d = 0; d < 64; d++) s += bv[d];
        wvs[96] = s;
    }
    __syncthreads();

    v8bf xa[2][3];
#pragma unroll
    for (int mt = 0; mt < 2; mt++) {
        int row = rowbase + mt * 16 + l15;
        const float* pr = power + (size_t)row * 64;
        float4 a0 = *(const float4*)(pr + quad * 8);
        float4 a1 = *(const float4*)(pr + quad * 8 + 4);
        xa[mt][0] = pk8(a0, a1);
        float d = d4(a0, *(const v4f*)(wvs + quad * 8))
                + d4(a1, *(const v4f*)(wvs + quad * 8 + 4));
        float4 a2 = *(const float4*)(pr + 32 + quad * 8);
        float4 a3 = *(const float4*)(pr + 32 + quad * 8 + 4);
        xa[mt][1] = pk8(a2, a3);
        d += d4(a2, *(const v4f*)(wvs + 32 + quad * 8))
           + d4(a3, *(const v4f*)(wvs + 32 + quad * 8 + 4));
        int ie = ele_i[row];
        int ia = azi_i[row];
        const float* tb = (quad < 2) ? (ele_t + ie * 16 + quad * 8)
                                     : (azi_t + ia * 16 + (quad - 2) * 8);
        float4 a4 = *(const float4*)tb;
        float4 a5 = *(const float4*)(tb + 4);
        xa[mt][2] = pk8(a4, a5);
        d += d4(a4, *(const v4f*)(wvs + 64 + quad * 8))
           + d4(a5, *(const v4f*)(wvs + 64 + quad * 8 + 4));
        d += __shfl_xor(d, 16);
        d += __shfl_xor(d, 32);
        if (quad == 0) vsum[wave * 32 + mt * 16 + l15] = d + wvs[96];
    }

    char* Sw = Kb + wave * 4096;
#pragma unroll 1
    for (int mtd = 0; mtd < 4; mtd++) {
        const bf16* wrow = WqL + (mtd * 16 + l15) * 96;
        v8bf wq3[3];
#pragma unroll
        for (int kt = 0; kt < 3; kt++)
            wq3[kt] = *(const v8bf*)(wrow + kt * 32 + quad * 8);
        float4 bq4 = *(const float4*)(bqL + mtd * 16 + quad * 4);
#pragma unroll
        for (int ntr = 0; ntr < 2; ntr++) {
            v4f acc = {0.f, 0.f, 0.f, 0.f};
#pragma unroll
            for (int kt = 0; kt < 3; kt++)
                acc = __builtin_amdgcn_mfma_f32_16x16x32_bf16(wq3[kt], xa[ntr][kt], acc, 0, 0, 0);
            int row = ntr * 16 + l15;
            v4bf o;
            o[0] = (bf16)((acc[0] + bq4.x) * SCALE);
            o[1] = (bf16)((acc[1] + bq4.y) * SCALE);
            o[2] = (bf16)((acc[2] + bq4.z) * SCALE);
            o[3] = (bf16)((acc[3] + bq4.w) * SCALE);
            *(v4bf*)(Sw + row * 128 +
                     ((((mtd * 2 + (quad >> 1)) ^ (row & 7)) << 4) | ((quad & 1) << 3))) = o;
        }
    }
    v8bf qf[2][2];
#pragma unroll
    for (int nt = 0; nt < 2; nt++)
#pragma unroll
        for (int kt = 0; kt < 2; kt++)
            qf[nt][kt] = *(const v8bf*)(Sw + (nt * 16 + l15) * 128 +
                                        (((kt * 4 + quad) ^ (l15 & 7)) << 4));

#pragma unroll 1
    for (int mtd = 0; mtd < 4; mtd++) {
        const bf16* wrow = WkL + (mtd * 16 + l15) * 96;
        v8bf wk3[3];
#pragma unroll
        for (int kt = 0; kt < 3; kt++)
            wk3[kt] = *(const v8bf*)(wrow + kt * 32 + quad * 8);
        float4 bk4 = *(const float4*)(bkL + mtd * 16 + quad * 4);
#pragma unroll
        for (int ntr = 0; ntr < 2; ntr++) {
            v4f acc = {0.f, 0.f, 0.f, 0.f};
#pragma unroll
            for (int kt = 0; kt < 3; kt++)
                acc = __builtin_amdgcn_mfma_f32_16x16x32_bf16(wk3[kt], xa[ntr][kt], acc, 0, 0, 0);
            int keyb = wave * 32 + ntr * 16 + l15;
            v4bf o;
            o[0] = (bf16)(acc[0] + bk4.x);
            o[1] = (bf16)(acc[1] + bk4.y);
            o[2] = (bf16)(acc[2] + bk4.z);
            o[3] = (bf16)(acc[3] + bk4.w);
            *(v4bf*)(Kb + keyb * 128 +
                     ((((mtd * 2 + (quad >> 1)) ^ (keyb & 7)) << 4) | ((quad & 1) << 3))) = o;
        }
    }
    __syncthreads();

    float osum[2] = {0.f, 0.f};
    float lsum[2] = {0.f, 0.f};
#pragma unroll 2
    for (int t = 0; t < 16; t++) {
        v8bf kf[2][2];
#pragma unroll
        for (int mtk = 0; mtk < 2; mtk++)
#pragma unroll
            for (int kt = 0; kt < 2; kt++) {
                int key = t * 32 + mtk * 16 + l15;
                kf[mtk][kt] = *(const v8bf*)(Kb + key * 128 + (((kt * 4 + quad) ^ (key & 7)) << 4));
            }
        v4f vs[2];
#pragma unroll
        for (int mtk = 0; mtk < 2; mtk++)
            vs[mtk] = *(const v4f*)(vsum + t * 32 + mtk * 16 + quad * 4);
#pragma unroll
        for (int mtk = 0; mtk < 2; mtk++) {
#pragma unroll
            for (int nt = 0; nt < 2; nt++) {
                v4f acc = {0.f, 0.f, 0.f, 0.f};
                acc = __builtin_amdgcn_mfma_f32_16x16x32_bf16(kf[mtk][0], qf[nt][0], acc, 0, 0, 0);
                acc = __builtin_amdgcn_mfma_f32_16x16x32_bf16(kf[mtk][1], qf[nt][1], acc, 0, 0, 0);
                float p0 = __builtin_amdgcn_exp2f(acc[0]);
                float p1 = __builtin_amdgcn_exp2f(acc[1]);
                float p2 = __builtin_amdgcn_exp2f(acc[2]);
                float p3 = __builtin_amdgcn_exp2f(acc[3]);
                lsum[nt] += (p0 + p1) + (p2 + p3);
                osum[nt] += ((p0 * vs[mtk][0] + p1 * vs[mtk][1]) +
                             (p2 * vs[mtk][2] + p3 * vs[mtk][3]));
            }
        }
    }

#pragma unroll
    for (int nt = 0; nt < 2; nt++) {
        float lv = lsum[nt];
        lv += __shfl_xor(lv, 16);
        lv += __shfl_xor(lv, 32);
        float ov = osum[nt];
        ov += __shfl_xor(ov, 16);
        ov += __shfl_xor(ov, 32);
        if (quad == 0) out[rowbase + nt * 16 + l15] = ov / lv;
    }
}

extern "C" void kernel_launch(void* const* d_in, const int* in_sizes, int n_in,
                              void* d_out, int out_size, void* d_ws, size_t ws_size,
                              hipStream_t stream) {
    const float* power = (const float*)d_in[0];
    const int*   ele_i = (const int*)d_in[1];
    // d_in[2] = range_indices: unused by the reference (positional reshape)
    const int*   azi_i = (const int*)d_in[3];
    const float* ele_t = (const float*)d_in[4];
    const float* azi_t = (const float*)d_in[5];
    const float* Wq = (const float*)d_in[6];
    const float* bq = (const float*)d_in[7];
    const float* Wk = (const float*)d_in[8];
    const float* bk = (const float*)d_in[9];
    const float* Wv = (const float*)d_in[10];
    const float* bv = (const float*)d_in[11];
    float* out = (float*)d_out;

    const size_t NQ = 131072;                  // 256 ranges x 512
    const size_t need = NQ * 16;               // float4 of partials per query

    if (ws_size >= need) {
        const int lds1 = 59392;                // Kb32K+vsum1K+wvs+WqL12K+WkL12K+biases
        (void)hipFuncSetAttribute(reinterpret_cast<const void*>(sda_split),
                                  hipFuncAttributeMaxDynamicSharedMemorySize, lds1);
        sda_split<<<512, 1024, lds1, stream>>>(power, ele_i, azi_i, ele_t, azi_t,
                                               Wq, bq, Wk, bk, Wv, bv,
                                               (float2*)d_ws);
        sda_combine<<<128, 1024, 0, stream>>>((const float4*)d_ws, out);
    } else {
        const int lds_bytes = 93184;
        (void)hipFuncSetAttribute(reinterpret_cast<const void*>(sda_mono),
                                  hipFuncAttributeMaxDynamicSharedMemorySize, lds_bytes);
        sda_mono<<<256, 1024, lds_bytes, stream>>>(power, ele_i, azi_i, ele_t, azi_t,
                                                   Wq, bq, Wk, bk, Wv, bv, out);
    }
}

// Round 7
// 110.736 us; speedup vs baseline: 1.1008x; 1.1008x over previous
//
#include <hip/hip_runtime.h>

// SparseDopplerAttention on gfx950 — R9 (base = R7, the proven best at ~31.7 us).
// Identity: out[q] = (sum_k P[q,k]*vsum[k]) / (sum_k P[q,k]),
//   vsum[k] = x[k] . colsum(Wv) + sum(bv)  (fp32) — V GEMM / PV GEMM eliminated.
// R8 post-mortem: occupancy lever refuted 3x; R6-k2 (attend-only ~22 us) shows
// Phase B dominates, and its floor is the quarter-rate trans pipe: 67M exp2
// = ~13.6 us/chip. R9 attacks everything AROUND the exps:
//   - packed v_pk_add/v_pk_fma accumulation (11 -> 8 VALU per 4 scores)
//   - explicit kf/vs double-buffer: next tile's ds_reads issue before the
//     current tile's exp burst, hiding LDS latency under trans-pipe time
//   - prologue: Wv col-sum distributed over 768 threads (was 96 threads x 64
//     serial loads); index->gather chains issued at kernel entry
// Everything else identical to R7 (LDS-staged bf16 weights, swizzled Kb,
// no-max log2-domain softmax, grid 256 x 1024).

#define SCALE 0.18033688011112042f   // log2(e)/8

typedef __bf16 bf16;
typedef bf16 v4bf __attribute__((ext_vector_type(4)));
typedef bf16 v8bf __attribute__((ext_vector_type(8)));
typedef float v4f __attribute__((ext_vector_type(4)));
typedef float v2f __attribute__((ext_vector_type(2)));

__device__ __forceinline__ v8bf pk8(float4 a, float4 b) {
    v8bf r;
    r[0] = (bf16)a.x; r[1] = (bf16)a.y; r[2] = (bf16)a.z; r[3] = (bf16)a.w;
    r[4] = (bf16)b.x; r[5] = (bf16)b.y; r[6] = (bf16)b.z; r[7] = (bf16)b.w;
    return r;
}
__device__ __forceinline__ float d4(float4 a, v4f w) {
    return a.x * w[0] + a.y * w[1] + a.z * w[2] + a.w * w[3];
}

__global__ __launch_bounds__(1024, 4)
void sda_kernel(const float* __restrict__ power,
                const int*   __restrict__ ele_i,
                const int*   __restrict__ azi_i,
                const float* __restrict__ ele_t,
                const float* __restrict__ azi_t,
                const float* __restrict__ Wq, const float* __restrict__ bq,
                const float* __restrict__ Wk, const float* __restrict__ bk,
                const float* __restrict__ Wv, const float* __restrict__ bv,
                float* __restrict__ out)
{
    extern __shared__ char smem[];
    char*  Kb   = smem;                      // 64 KB: K [key][dim] bf16, 128 B rows, blk16 ^= key&7
    float* vsum = (float*)(smem + 65536);    // 512 f32
    float* wvs  = (float*)(smem + 67584);    // 96 col-sums of Wv + [96]=sum(bv)
    bf16*  WqL  = (bf16*)(smem + 68096);     // 12 KB: Wq bf16 row-major [64][96]
    bf16*  WkL  = (bf16*)(smem + 80384);     // 12 KB: Wk bf16 row-major [64][96]
    float* bqL  = (float*)(smem + 92672);    // 64 f32
    float* bkL  = (float*)(smem + 92928);    // 64 f32
    float* pbuf = (float*)smem;              // prologue-only: 832 f32 inside Kb

    const int tid  = threadIdx.x;
    const int wave = tid >> 6;
    const int lane = tid & 63;
    const int l15  = lane & 15;
    const int quad = lane >> 4;
    const int rowbase = blockIdx.x * 512 + wave * 32;   // this wave's 32 rows

    // ---- issue cold loads first: indices -> power rows -> table gathers ----
    int IE[2], IA[2];
#pragma unroll
    for (int mt = 0; mt < 2; mt++) {
        int row = rowbase + mt * 16 + l15;
        IE[mt] = ele_i[row];
        IA[mt] = azi_i[row];
    }
    float4 A[2][4];
#pragma unroll
    for (int mt = 0; mt < 2; mt++) {
        const float* pr = power + (size_t)(rowbase + mt * 16 + l15) * 64;
        A[mt][0] = *(const float4*)(pr + quad * 8);
        A[mt][1] = *(const float4*)(pr + quad * 8 + 4);
        A[mt][2] = *(const float4*)(pr + 32 + quad * 8);
        A[mt][3] = *(const float4*)(pr + 32 + quad * 8 + 4);
    }
    float4 T0[2], T1[2];
#pragma unroll
    for (int mt = 0; mt < 2; mt++) {
        const float* tb = (quad < 2) ? (ele_t + IE[mt] * 16 + quad * 8)
                                     : (azi_t + IA[mt] * 16 + (quad - 2) * 8);
        T0[mt] = *(const float4*)tb;
        T1[mt] = *(const float4*)(tb + 4);
    }

    // ---- prologue: weights -> bf16 LDS; Wv col-sum partials (768 thr); bv; biases ----
#pragma unroll
    for (int i = 0; i < 6; i++) {
        int idx = tid + i * 1024;            // 6144 elements each
        WqL[idx] = (bf16)Wq[idx];
        WkL[idx] = (bf16)Wk[idx];
    }
    if (tid < 768) {
        int c = tid % 96;
        int g = tid / 96;                    // 0..7, rows g*8..g*8+7
        float s = 0.f;
#pragma unroll
        for (int r = 0; r < 8; r++) s += Wv[(g * 8 + r) * 96 + c];
        pbuf[g * 96 + c] = s;
    } else if (tid < 832) {
        pbuf[768 + (tid - 768)] = bv[tid - 768];
    }
    if (tid < 64) { bqL[tid] = bq[tid]; bkL[tid] = bk[tid]; }
    __syncthreads();                         // BAR1: staging + partials done
    if (tid < 96) {
        float s = 0.f;
#pragma unroll
        for (int g = 0; g < 8; g++) s += pbuf[g * 96 + tid];
        wvs[tid] = s;
    } else if (tid == 96) {
        float s = 0.f;
#pragma unroll
        for (int j = 0; j < 64; j++) s += pbuf[768 + j];
        wvs[96] = s;
    }
    __syncthreads();                         // BAR2: wvs ready (pbuf dead)

    // ---- x fragments (from regs) + fp32 vsum ----
    v4f w0 = *(const v4f*)(wvs + quad * 8);
    v4f w1 = *(const v4f*)(wvs + quad * 8 + 4);
    v4f w2 = *(const v4f*)(wvs + 32 + quad * 8);
    v4f w3 = *(const v4f*)(wvs + 32 + quad * 8 + 4);
    v4f w4 = *(const v4f*)(wvs + 64 + quad * 8);
    v4f w5 = *(const v4f*)(wvs + 64 + quad * 8 + 4);
    const float bvs = wvs[96];

    v8bf xa[2][3];
#pragma unroll
    for (int mt = 0; mt < 2; mt++) {
        xa[mt][0] = pk8(A[mt][0], A[mt][1]);
        xa[mt][1] = pk8(A[mt][2], A[mt][3]);
        xa[mt][2] = pk8(T0[mt], T1[mt]);
        float d = d4(A[mt][0], w0) + d4(A[mt][1], w1) + d4(A[mt][2], w2)
                + d4(A[mt][3], w3) + d4(T0[mt], w4) + d4(T1[mt], w5);
        d += __shfl_xor(d, 16);
        d += __shfl_xor(d, 32);
        if (quad == 0) vsum[wave * 32 + mt * 16 + l15] = d + bvs;
    }

    // ---- Q^T = Wq @ x^T (weights from LDS), fold SCALE, transpose via own K region ----
    char* Sw = Kb + wave * 4096;   // this wave's 32 K-rows; used first as Q scratch
#pragma unroll 1
    for (int mtd = 0; mtd < 4; mtd++) {
        const bf16* wrow = WqL + (mtd * 16 + l15) * 96;
        v8bf wq3[3];
#pragma unroll
        for (int kt = 0; kt < 3; kt++)
            wq3[kt] = *(const v8bf*)(wrow + kt * 32 + quad * 8);
        float4 bq4 = *(const float4*)(bqL + mtd * 16 + quad * 4);
#pragma unroll
        for (int ntr = 0; ntr < 2; ntr++) {
            v4f acc = {0.f, 0.f, 0.f, 0.f};
#pragma unroll
            for (int kt = 0; kt < 3; kt++)
                acc = __builtin_amdgcn_mfma_f32_16x16x32_bf16(wq3[kt], xa[ntr][kt], acc, 0, 0, 0);
            int row = ntr * 16 + l15;   // local query
            v4bf o;
            o[0] = (bf16)((acc[0] + bq4.x) * SCALE);
            o[1] = (bf16)((acc[1] + bq4.y) * SCALE);
            o[2] = (bf16)((acc[2] + bq4.z) * SCALE);
            o[3] = (bf16)((acc[3] + bq4.w) * SCALE);
            *(v4bf*)(Sw + row * 128 +
                     ((((mtd * 2 + (quad >> 1)) ^ (row & 7)) << 4) | ((quad & 1) << 3))) = o;
        }
    }
    v8bf qf[2][2];
#pragma unroll
    for (int nt = 0; nt < 2; nt++)
#pragma unroll
        for (int kt = 0; kt < 2; kt++)
            qf[nt][kt] = *(const v8bf*)(Sw + (nt * 16 + l15) * 128 +
                                        (((kt * 4 + quad) ^ (l15 & 7)) << 4));

    // ---- K^T = Wk @ x^T (weights from LDS), write over the scratch ----
#pragma unroll 1
    for (int mtd = 0; mtd < 4; mtd++) {
        const bf16* wrow = WkL + (mtd * 16 + l15) * 96;
        v8bf wk3[3];
#pragma unroll
        for (int kt = 0; kt < 3; kt++)
            wk3[kt] = *(const v8bf*)(wrow + kt * 32 + quad * 8);
        float4 bk4 = *(const float4*)(bkL + mtd * 16 + quad * 4);
#pragma unroll
        for (int ntr = 0; ntr < 2; ntr++) {
            v4f acc = {0.f, 0.f, 0.f, 0.f};
#pragma unroll
            for (int kt = 0; kt < 3; kt++)
                acc = __builtin_amdgcn_mfma_f32_16x16x32_bf16(wk3[kt], xa[ntr][kt], acc, 0, 0, 0);
            int keyb = wave * 32 + ntr * 16 + l15;
            v4bf o;
            o[0] = (bf16)(acc[0] + bk4.x);
            o[1] = (bf16)(acc[1] + bk4.y);
            o[2] = (bf16)(acc[2] + bk4.z);
            o[3] = (bf16)(acc[3] + bk4.w);
            *(v4bf*)(Kb + keyb * 128 +
                     ((((mtd * 2 + (quad >> 1)) ^ (keyb & 7)) << 4) | ((quad & 1) << 3))) = o;
        }
    }
    __syncthreads();                         // BAR3: K tile + vsum complete

    // ---- Phase B: S^T = K @ Q^T, exp2, packed weighted accumulate ----
    // Explicit double-buffer: tile t+1's ds_reads issue before tile t's exp
    // burst, so LDS latency hides under the trans-pipe time.
#define LOADT(t, K, V)                                                          \
    {                                                                           \
        _Pragma("unroll")                                                       \
        for (int mtk = 0; mtk < 2; mtk++) {                                     \
            int key = (t) * 32 + mtk * 16 + l15;                                \
            _Pragma("unroll")                                                   \
            for (int kt = 0; kt < 2; kt++)                                      \
                K[mtk][kt] = *(const v8bf*)(Kb + key * 128 +                    \
                             (((kt * 4 + quad) ^ (key & 7)) << 4));             \
            V[mtk] = *(const v4f*)(vsum + (t) * 32 + mtk * 16 + quad * 4);      \
        }                                                                       \
    }

#define COMPUTE(K, V)                                                           \
    {                                                                           \
        _Pragma("unroll")                                                       \
        for (int mtk = 0; mtk < 2; mtk++) {                                     \
            v2f v01 = {V[mtk][0], V[mtk][1]};                                   \
            v2f v23 = {V[mtk][2], V[mtk][3]};                                   \
            _Pragma("unroll")                                                   \
            for (int nt = 0; nt < 2; nt++) {                                    \
                v4f acc = {0.f, 0.f, 0.f, 0.f};                                 \
                acc = __builtin_amdgcn_mfma_f32_16x16x32_bf16(K[mtk][0], qf[nt][0], acc, 0, 0, 0); \
                acc = __builtin_amdgcn_mfma_f32_16x16x32_bf16(K[mtk][1], qf[nt][1], acc, 0, 0, 0); \
                v2f p01 = {__builtin_amdgcn_exp2f(acc[0]),                      \
                           __builtin_amdgcn_exp2f(acc[1])};                     \
                v2f p23 = {__builtin_amdgcn_exp2f(acc[2]),                      \
                           __builtin_amdgcn_exp2f(acc[3])};                     \
                lacc[nt] += p01 + p23;              /* v_pk_add_f32 */          \
                oacc[nt] += p01 * v01 + p23 * v23;  /* v_pk_fma_f32 */          \
            }                                                                   \
        }                                                                       \
    }

    v8bf kA[2][2], kB[2][2];
    v4f  vA[2], vB[2];
    v2f lacc[2] = {{0.f, 0.f}, {0.f, 0.f}};
    v2f oacc[2] = {{0.f, 0.f}, {0.f, 0.f}};

    LOADT(0, kA, vA);
#pragma unroll 1
    for (int tp = 0; tp < 7; tp++) {
        LOADT(2 * tp + 1, kB, vB);
        COMPUTE(kA, vA);
        LOADT(2 * tp + 2, kA, vA);
        COMPUTE(kB, vB);
    }
    LOADT(15, kB, vB);
    COMPUTE(kA, vA);
    COMPUTE(kB, vB);

    // ---- epilogue: reduce over key-quads, out = osum/lsum ----
#pragma unroll
    for (int nt = 0; nt < 2; nt++) {
        float lv = lacc[nt][0] + lacc[nt][1];
        lv += __shfl_xor(lv, 16);
        lv += __shfl_xor(lv, 32);
        float ov = oacc[nt][0] + oacc[nt][1];
        ov += __shfl_xor(ov, 16);
        ov += __shfl_xor(ov, 32);
        if (quad == 0) out[rowbase + nt * 16 + l15] = ov / lv;
    }
#undef LOADT
#undef COMPUTE
}

extern "C" void kernel_launch(void* const* d_in, const int* in_sizes, int n_in,
                              void* d_out, int out_size, void* d_ws, size_t ws_size,
                              hipStream_t stream) {
    const float* power = (const float*)d_in[0];
    const int*   ele_i = (const int*)d_in[1];
    // d_in[2] = range_indices: unused by the reference (positional reshape)
    const int*   azi_i = (const int*)d_in[3];
    const float* ele_t = (const float*)d_in[4];
    const float* azi_t = (const float*)d_in[5];
    const float* Wq = (const float*)d_in[6];
    const float* bq = (const float*)d_in[7];
    const float* Wk = (const float*)d_in[8];
    const float* bk = (const float*)d_in[9];
    const float* Wv = (const float*)d_in[10];
    const float* bv = (const float*)d_in[11];
    float* out = (float*)d_out;

    // Kb 64K + vsum 2K + wvs 512B + WqL 12K + WkL 12K + bqL 256B + bkL 256B
    const int lds_bytes = 93184;
    (void)hipFuncSetAttribute(reinterpret_cast<const void*>(sda_kernel),
                              hipFuncAttributeMaxDynamicSharedMemorySize, lds_bytes);
    sda_kernel<<<256, 1024, lds_bytes, stream>>>(power, ele_i, azi_i, ele_t, azi_t,
                                                 Wq, bq, Wk, bk, Wv, bv, out);
}